// Round 1
// baseline (125407.227 us; speedup 1.0000x reference)
//
#include <hip/hip_runtime.h>
#include <hip/hip_bf16.h>

// Sizes from the reference
#define T_   4096
#define E_   8
#define NA   16    // phase A workgroups (must all be co-resident; 16 << 256 CUs)
#define NC   8     // phase C workgroups

__device__ __forceinline__ float sigm(float x)  { return 1.0f / (1.0f + __expf(-x)); }
// tanh via exp2-based expf; no NaN at +/-inf: e->inf => 1, e->0 => -1
__device__ __forceinline__ float tanh_(float x) { return 1.0f - 2.0f / (__expf(2.0f * x) + 1.0f); }

#define FMA_8(ACC, W, VA, VB)                                   \
  ACC[0] = fmaf((W), (VA).x, ACC[0]); ACC[1] = fmaf((W), (VA).y, ACC[1]); \
  ACC[2] = fmaf((W), (VA).z, ACC[2]); ACC[3] = fmaf((W), (VA).w, ACC[3]); \
  ACC[4] = fmaf((W), (VB).x, ACC[4]); ACC[5] = fmaf((W), (VB).y, ACC[5]); \
  ACC[6] = fmaf((W), (VB).z, ACC[6]); ACC[7] = fmaf((W), (VB).w, ACC[7]);

// ---------------------------------------------------------------------------
// initK: build K-major (transposed) weight copies in ws + zero barriers.
// Layouts: wt_p0[k][1024] k<192 = Wih_p0, else Whh_p0 (k-192)
//          wt_p1[k][1024] k<256 = Wih_p1, else Whh_p1
//          wt_c0/wt_c1[k][512] k<128 = Wih_c*, else Whh_c*
//          wt_o1[k][512] = Wih_o[:, k]       (k in [0,256): group_dec part)
//          wt_oh[k][512] = Whh_o[:, k]       (k in [0,128))
//          wt_o2[k][512] = Wih_o[:, 256+k]   (k in [0,192): x part)
// ---------------------------------------------------------------------------
__global__ void initK(const float* __restrict__ Wih_p0, const float* __restrict__ Whh_p0,
                      const float* __restrict__ Wih_p1, const float* __restrict__ Whh_p1,
                      const float* __restrict__ Wih_c0, const float* __restrict__ Whh_c0,
                      const float* __restrict__ Wih_c1, const float* __restrict__ Whh_c1,
                      const float* __restrict__ Wih_o,  const float* __restrict__ Whh_o,
                      float* wt_p0, float* wt_p1, float* wt_c0, float* wt_c1,
                      float* wt_o1, float* wt_oh, float* wt_o2, int* bars) {
  const int NTOT = 458752 + 524288 + 131072 + 131072 + 131072 + 65536 + 98304 + 12288;
  for (int i = blockIdx.x * blockDim.x + threadIdx.x; i < NTOT; i += gridDim.x * blockDim.x) {
    int idx = i;
    if (idx < 458752) { int k = idx >> 10, g = idx & 1023;
      wt_p0[idx] = (k < 192) ? Wih_p0[g * 192 + k] : Whh_p0[g * 256 + (k - 192)]; continue; }
    idx -= 458752;
    if (idx < 524288) { int k = idx >> 10, g = idx & 1023;
      wt_p1[idx] = (k < 256) ? Wih_p1[g * 256 + k] : Whh_p1[g * 256 + (k - 256)]; continue; }
    idx -= 524288;
    if (idx < 131072) { int k = idx >> 9, r = idx & 511;
      wt_c0[idx] = (k < 128) ? Wih_c0[r * 128 + k] : Whh_c0[r * 128 + (k - 128)]; continue; }
    idx -= 131072;
    if (idx < 131072) { int k = idx >> 9, r = idx & 511;
      wt_c1[idx] = (k < 128) ? Wih_c1[r * 128 + k] : Whh_c1[r * 128 + (k - 128)]; continue; }
    idx -= 131072;
    if (idx < 131072) { int k = idx >> 9, r = idx & 511;
      wt_o1[idx] = Wih_o[r * 448 + k]; continue; }
    idx -= 131072;
    if (idx < 65536)  { int k = idx >> 9, r = idx & 511;
      wt_oh[idx] = Whh_o[r * 128 + k]; continue; }
    idx -= 65536;
    if (idx < 98304)  { int k = idx >> 9, r = idx & 511;
      wt_o2[idx] = Wih_o[r * 448 + 256 + k]; continue; }
    idx -= 98304;
    bars[idx] = 0;
  }
}

// ---------------------------------------------------------------------------
// opre2K: parallel over t. opre2[t][e][512] = Wih_o[:,256:448] @ x(t,e)  (bf16)
// x(t,e) = [features[t][0:128] ; features[t][128+e*64 : 128+(e+1)*64]]
// ---------------------------------------------------------------------------
__global__ void opre2K(const float* __restrict__ feat, const float* __restrict__ wt_o2,
                       __hip_bfloat16* __restrict__ opre2) {
  __shared__ float xb[192 * 8];
  const int t = blockIdx.x, tid = threadIdx.x;
  const float* ft = feat + (size_t)t * 640;
  for (int idx = tid; idx < 192 * 8; idx += 256) {
    int k = idx >> 3, e = idx & 7;
    xb[idx] = (k < 128) ? ft[k] : ft[128 + e * 64 + (k - 128)];
  }
  __syncthreads();
  const int r = tid;
  float A0[8] = {0,0,0,0,0,0,0,0};
  float A1[8] = {0,0,0,0,0,0,0,0};
  const float4* x4 = (const float4*)xb;
  #pragma unroll 2
  for (int k = 0; k < 192; ++k) {
    float w0 = wt_o2[k * 512 + r];
    float w1 = wt_o2[k * 512 + 256 + r];
    float4 a = x4[k * 2], b = x4[k * 2 + 1];
    FMA_8(A0, w0, a, b);
    FMA_8(A1, w1, a, b);
  }
  #pragma unroll
  for (int e = 0; e < 8; ++e) {
    opre2[((size_t)t * 8 + e) * 512 + r]       = __float2bfloat16(A0[e]);
    opre2[((size_t)t * 8 + e) * 512 + 256 + r] = __float2bfloat16(A1[e]);
  }
}

// ---------------------------------------------------------------------------
// phaseA: persistent, NA WGs, sequential over t. Two L2-atomic barriers/step.
// WG owns h-slice j in [wg*16, wg*16+16) of both pre layers.
// Thread map for dots: r6 = tid&63 -> (gate = r6>>4, jl = r6&15); kq = tid>>6
// K split 4-way, each thread accumulates all 8 elements (float4 LDS reads).
// ---------------------------------------------------------------------------
__launch_bounds__(256, 1)
__global__ void phaseA(const float* __restrict__ feat,
                       const float* __restrict__ pre_h0, const float* __restrict__ pre_c0,
                       const float* __restrict__ wt_p0, const float* __restrict__ wt_p1,
                       const float* __restrict__ b_p0, const float* __restrict__ b_p1,
                       const float* __restrict__ Wfc, const float* __restrict__ bfc,
                       float* __restrict__ hA, float* __restrict__ pre_out,
                       int* __restrict__ barA) {
  __shared__ float xl [448 * 8];   // [k][e] inputs for layer0: x(192) ++ h0(t-1)(256)
  __shared__ float xl2[512 * 8];   // [k][e] inputs for layer1: h0(t)(256) ++ h1(t-1)(256)
  __shared__ float gl [4 * 64 * 8]; // [kq][row64][e] partial sums
  const int wg = blockIdx.x, tid = threadIdx.x;
  const int r6 = tid & 63, kq = tid >> 6;
  const int col = ((r6 >> 4) << 8) + wg * 16 + (r6 & 15);  // row in [0,1024)
  const int ue = tid >> 4, uj = tid & 15;                  // update thread (tid<128)
  const int j = wg * 16 + uj;
  float c0reg = 0.f, c1reg = 0.f;
  float bi0=0,bf0=0,bg0=0,bo0=0,bi1=0,bf1=0,bg1=0,bo1=0;
  if (tid < 128) {
    c0reg = pre_c0[(ue * 2 + 0) * 256 + j];
    c1reg = pre_c0[(ue * 2 + 1) * 256 + j];
    bi0 = b_p0[j]; bf0 = b_p0[256 + j]; bg0 = b_p0[512 + j]; bo0 = b_p0[768 + j];
    bi1 = b_p1[j]; bf1 = b_p1[256 + j]; bg1 = b_p1[512 + j]; bo1 = b_p1[768 + j];
  }
  // h1(-1) = pre_h0[:,1,:] into xl2 upper half
  for (int idx = tid; idx < 2048; idx += 256) {
    int e = idx >> 8, k = idx & 255;
    xl2[(256 + k) * 8 + e] = pre_h0[(e * 2 + 1) * 256 + k];
  }
  for (int t = 0; t < T_; ++t) {
    const int pw = t & 1, pr = pw ^ 1;
    const float* ft = feat + (size_t)t * 640;
    for (int idx = tid; idx < 448 * 8; idx += 256) {
      int k = idx >> 3, e = idx & 7;
      float v;
      if (k < 128)      v = ft[k];
      else if (k < 192) v = ft[128 + e * 64 + (k - 128)];
      else v = (t == 0) ? pre_h0[(e * 2) * 256 + (k - 192)]
                        : hA[((pr * 2 + 0) * 8 + e) * 256 + (k - 192)];
      xl[idx] = v;
    }
    __syncthreads();
    { // S1 partial dots, K=448 in 4 chunks of 112
      float A[8] = {0,0,0,0,0,0,0,0};
      const float4* x4 = (const float4*)xl;
      const int kb = kq * 112, ke = kb + 112;
      #pragma unroll 4
      for (int k = kb; k < ke; ++k) {
        float w = wt_p0[k * 1024 + col];
        float4 a = x4[k * 2], b = x4[k * 2 + 1];
        FMA_8(A, w, a, b);
      }
      float4* g4 = (float4*)gl;
      g4[(kq * 64 + r6) * 2]     = make_float4(A[0], A[1], A[2], A[3]);
      g4[(kq * 64 + r6) * 2 + 1] = make_float4(A[4], A[5], A[6], A[7]);
    }
    __syncthreads();
    if (tid < 128) {
      float s[4];
      #pragma unroll
      for (int g = 0; g < 4; ++g) {
        int rg = g * 16 + uj;
        s[g] = gl[(0 * 64 + rg) * 8 + ue] + gl[(1 * 64 + rg) * 8 + ue]
             + gl[(2 * 64 + rg) * 8 + ue] + gl[(3 * 64 + rg) * 8 + ue];
      }
      float c2 = sigm(s[1] + bf0) * c0reg + sigm(s[0] + bi0) * tanh_(s[2] + bg0);
      float h2 = sigm(s[3] + bo0) * tanh_(c2);
      c0reg = c2;
      hA[((pw * 2 + 0) * 8 + ue) * 256 + j] = h2;
    }
    __syncthreads();   // HW drains vmem before s_barrier; tid0's ACQ_REL RMW flushes/invalidates L2
    if (tid == 0) {
      __hip_atomic_fetch_add(&barA[2 * t], 1, __ATOMIC_ACQ_REL, __HIP_MEMORY_SCOPE_AGENT);
      while (__hip_atomic_load(&barA[2 * t], __ATOMIC_ACQUIRE, __HIP_MEMORY_SCOPE_AGENT) < NA)
        __builtin_amdgcn_s_sleep(2);
    }
    __syncthreads();
    // gather full h0(t) into xl2 lower half
    for (int idx = tid; idx < 2048; idx += 256) {
      int e = idx >> 8, k = idx & 255;
      xl2[k * 8 + e] = hA[((pw * 2 + 0) * 8 + e) * 256 + k];
    }
    __syncthreads();
    { // S2 partial dots, K=512 in 4 chunks of 128
      float A[8] = {0,0,0,0,0,0,0,0};
      const float4* x4 = (const float4*)xl2;
      const int kb = kq * 128, ke = kb + 128;
      #pragma unroll 4
      for (int k = kb; k < ke; ++k) {
        float w = wt_p1[k * 1024 + col];
        float4 a = x4[k * 2], b = x4[k * 2 + 1];
        FMA_8(A, w, a, b);
      }
      float4* g4 = (float4*)gl;
      g4[(kq * 64 + r6) * 2]     = make_float4(A[0], A[1], A[2], A[3]);
      g4[(kq * 64 + r6) * 2 + 1] = make_float4(A[4], A[5], A[6], A[7]);
    }
    __syncthreads();
    if (tid < 128) {
      float s[4];
      #pragma unroll
      for (int g = 0; g < 4; ++g) {
        int rg = g * 16 + uj;
        s[g] = gl[(0 * 64 + rg) * 8 + ue] + gl[(1 * 64 + rg) * 8 + ue]
             + gl[(2 * 64 + rg) * 8 + ue] + gl[(3 * 64 + rg) * 8 + ue];
      }
      float c2 = sigm(s[1] + bf1) * c1reg + sigm(s[0] + bi1) * tanh_(s[2] + bg1);
      float h2 = sigm(s[3] + bo1) * tanh_(c2);
      c1reg = c2;
      hA[((pw * 2 + 1) * 8 + ue) * 256 + j] = h2;
    }
    __syncthreads();
    if (tid == 0) {
      __hip_atomic_fetch_add(&barA[2 * t + 1], 1, __ATOMIC_ACQ_REL, __HIP_MEMORY_SCOPE_AGENT);
      while (__hip_atomic_load(&barA[2 * t + 1], __ATOMIC_ACQUIRE, __HIP_MEMORY_SCOPE_AGENT) < NA)
        __builtin_amdgcn_s_sleep(2);
    }
    __syncthreads();
    // full h1(t) into xl2 upper half: serves fc(t) now and S2(t+1) next iter
    for (int idx = tid; idx < 2048; idx += 256) {
      int e = idx >> 8, k = idx & 255;
      xl2[(256 + k) * 8 + e] = hA[((pw * 2 + 1) * 8 + e) * 256 + k];
    }
    __syncthreads();
    if (tid < 64) {  // fc: WG computes cols [wg*8, wg*8+8)
      int c = wg * 8 + (tid >> 3), e = tid & 7;
      float acc = bfc[c];
      const float* wrow = Wfc + c * 256;
      #pragma unroll 4
      for (int k = 0; k < 256; ++k) acc = fmaf(wrow[k], xl2[(256 + k) * 8 + e], acc);
      pre_out[((size_t)t * 8 + e) * 128 + c] = (acc > 0.f) ? acc : 0.05f * acc;
    }
    __syncthreads();
  }
}

// ---------------------------------------------------------------------------
// comm cell for phase B: 8 timesteps batched per WG, all state in LDS [k][8]
// ---------------------------------------------------------------------------
__device__ __forceinline__ void comm_cell(
    const float* __restrict__ wt, const float* __restrict__ bias,
    const float* xin, float* hL, float* cL, float* glb, float* hout,
    float alpha, int tid) {
  const int r = tid;
  float A0[8] = {0,0,0,0,0,0,0,0};
  float A1[8] = {0,0,0,0,0,0,0,0};
  const float4* x4 = (const float4*)xin;
  #pragma unroll 2
  for (int k = 0; k < 128; ++k) {
    float w0 = wt[k * 512 + r];
    float w1 = wt[k * 512 + 256 + r];
    float4 a = x4[k * 2], b = x4[k * 2 + 1];
    FMA_8(A0, w0, a, b);
    FMA_8(A1, w1, a, b);
  }
  const float4* h4 = (const float4*)hL;
  #pragma unroll 2
  for (int k = 0; k < 128; ++k) {
    float w0 = wt[(128 + k) * 512 + r];
    float w1 = wt[(128 + k) * 512 + 256 + r];
    float4 a = h4[k * 2], b = h4[k * 2 + 1];
    FMA_8(A0, w0, a, b);
    FMA_8(A1, w1, a, b);
  }
  #pragma unroll
  for (int tt = 0; tt < 8; ++tt) { glb[r * 8 + tt] = A0[tt]; glb[(256 + r) * 8 + tt] = A1[tt]; }
  __syncthreads();
  for (int idx = tid; idx < 1024; idx += 256) {
    int jj = idx >> 3, tt = idx & 7;
    float gi = glb[jj * 8 + tt]         + bias[jj];
    float gf = glb[(128 + jj) * 8 + tt] + bias[128 + jj];
    float gg = glb[(256 + jj) * 8 + tt] + bias[256 + jj];
    float go = glb[(384 + jj) * 8 + tt] + bias[384 + jj];
    float cold = cL[idx], hold = hL[idx];
    float c2 = sigm(gf) * cold + sigm(gi) * tanh_(gg);
    float h2 = sigm(go) * tanh_(c2);
    float hb = fmaf(alpha, h2 - hold, hold);   // (1-a)*h + a*h2
    float cb = fmaf(alpha, c2 - cold, cold);
    hL[idx] = hb; cL[idx] = cb;
    if (hout) hout[idx] = hb;
  }
  __syncthreads();
}

// ---------------------------------------------------------------------------
// phaseB: parallel over t (8 timesteps / WG). Also emits
// opre1[t][512] = Wih_o[:, :256] @ group_dec(t) + b_o  (cc already in LDS)
// ---------------------------------------------------------------------------
__launch_bounds__(256, 2)
__global__ void phaseB(const float* __restrict__ pre_out,
                       const float* __restrict__ wt_c0, const float* __restrict__ wt_c1,
                       const float* __restrict__ b_c0, const float* __restrict__ b_c1,
                       const float* __restrict__ wt_o1, const float* __restrict__ b_o,
                       float* __restrict__ opre1) {
  __shared__ float pol[128 * 8];
  __shared__ float ch0[128 * 8], cc0[128 * 8], ch1[128 * 8], cc1[128 * 8];
  __shared__ float h0b[128 * 8];
  __shared__ float glb[512 * 8];
  const int wg = blockIdx.x, tid = threadIdx.x;
  const int t0 = wg * 8;
  for (int idx = tid; idx < 1024; idx += 256) { ch0[idx]=0.f; cc0[idx]=0.f; ch1[idx]=0.f; cc1[idx]=0.f; }
  __syncthreads();
  float alpha = 1.0f;
  for (int rd = 0; rd < 3; ++rd) {
    for (int e = 0; e < E_; ++e) {
      for (int idx = tid; idx < 1024; idx += 256) {
        int tt = idx >> 7, k = idx & 127;
        pol[k * 8 + tt] = pre_out[(((size_t)(t0 + tt)) * 8 + e) * 128 + k];
      }
      __syncthreads();
      comm_cell(wt_c0, b_c0, pol, ch0, cc0, glb, h0b, alpha, tid);
      comm_cell(wt_c1, b_c1, h0b, ch1, cc1, glb, nullptr, alpha, tid);
    }
    alpha *= 0.333f;
  }
  { // opre1
    const int r = tid;
    float A0[8], A1[8];
    #pragma unroll
    for (int tt = 0; tt < 8; ++tt) { A0[tt] = b_o[r]; A1[tt] = b_o[256 + r]; }
    const float4* c04 = (const float4*)cc0;
    const float4* c14 = (const float4*)cc1;
    #pragma unroll 2
    for (int k = 0; k < 128; ++k) {
      float w0 = wt_o1[k * 512 + r], w1 = wt_o1[k * 512 + 256 + r];
      float4 a = c04[k * 2], b = c04[k * 2 + 1];
      FMA_8(A0, w0, a, b);
      FMA_8(A1, w1, a, b);
    }
    #pragma unroll 2
    for (int k = 0; k < 128; ++k) {
      float w0 = wt_o1[(128 + k) * 512 + r], w1 = wt_o1[(128 + k) * 512 + 256 + r];
      float4 a = c14[k * 2], b = c14[k * 2 + 1];
      FMA_8(A0, w0, a, b);
      FMA_8(A1, w1, a, b);
    }
    #pragma unroll
    for (int tt = 0; tt < 8; ++tt) {
      opre1[((size_t)(t0 + tt)) * 512 + r]       = A0[tt];
      opre1[((size_t)(t0 + tt)) * 512 + 256 + r] = A1[tt];
    }
  }
}

// ---------------------------------------------------------------------------
// phaseC: persistent, NC WGs, sequential over t. Whh_o slice staged in LDS.
// gates = opre1[t] + opre2[t][e] + Whh_o @ oh(t-1); one barrier/step.
// ---------------------------------------------------------------------------
__launch_bounds__(256, 1)
__global__ void phaseC(const float* __restrict__ opre1, const __hip_bfloat16* __restrict__ opre2,
                       const float* __restrict__ wt_oh, const float* __restrict__ out_h0,
                       const float* __restrict__ out_c0,
                       float* __restrict__ oh_g, int* __restrict__ barC) {
  __shared__ float whl[128 * 64];  // [k][row64] weight slice
  __shared__ float ohl[128 * 8];   // [k][e] oh(t-1)
  __shared__ float gl [64 * 8];
  const int wg = blockIdx.x, tid = threadIdx.x;
  const int r6 = tid & 63, ep = tid >> 6;
  const int e0 = 2 * ep, e1 = e0 + 1;
  const int grow = ((r6 >> 4) << 7) + wg * 16 + (r6 & 15);  // row in [0,512)
  const int ue = tid >> 4, uj = tid & 15;
  const int j = wg * 16 + uj;
  for (int idx = tid; idx < 8192; idx += 256) {
    int k = idx >> 6, rr = idx & 63;
    int c = ((rr >> 4) << 7) + wg * 16 + (rr & 15);
    whl[idx] = wt_oh[k * 512 + c];
  }
  for (int idx = tid; idx < 1024; idx += 256) {
    int e = idx >> 7, k = idx & 127;
    ohl[k * 8 + e] = out_h0[e * 128 + k];
  }
  float ocreg = (tid < 128) ? out_c0[ue * 128 + j] : 0.f;
  __syncthreads();
  for (int t = 0; t < T_; ++t) {
    float a0 = opre1[(size_t)t * 512 + grow] + __bfloat162float(opre2[((size_t)t * 8 + e0) * 512 + grow]);
    float a1 = opre1[(size_t)t * 512 + grow] + __bfloat162float(opre2[((size_t)t * 8 + e1) * 512 + grow]);
    const float2* o2 = (const float2*)ohl;
    #pragma unroll 4
    for (int k = 0; k < 128; ++k) {
      float w = whl[k * 64 + r6];
      float2 x = o2[k * 4 + ep];
      a0 = fmaf(w, x.x, a0); a1 = fmaf(w, x.y, a1);
    }
    gl[r6 * 8 + e0] = a0; gl[r6 * 8 + e1] = a1;
    __syncthreads();
    if (tid < 128) {
      float gi = gl[uj * 8 + ue],        gf = gl[(16 + uj) * 8 + ue];
      float gg = gl[(32 + uj) * 8 + ue], go = gl[(48 + uj) * 8 + ue];
      float c2 = sigm(gf) * ocreg + sigm(gi) * tanh_(gg);
      float h2 = sigm(go) * tanh_(c2);
      ocreg = c2;
      oh_g[((size_t)t * 8 + ue) * 128 + j] = h2;
    }
    __syncthreads();
    if (tid == 0) {
      __hip_atomic_fetch_add(&barC[t], 1, __ATOMIC_ACQ_REL, __HIP_MEMORY_SCOPE_AGENT);
      while (__hip_atomic_load(&barC[t], __ATOMIC_ACQUIRE, __HIP_MEMORY_SCOPE_AGENT) < NC)
        __builtin_amdgcn_s_sleep(2);
    }
    __syncthreads();
    for (int idx = tid; idx < 1024; idx += 256) {
      int e = idx >> 7, k = idx & 127;
      ohl[k * 8 + e] = oh_g[((size_t)t * 8 + e) * 128 + k];
    }
    __syncthreads();
  }
}

// ---------------------------------------------------------------------------
// phaseD: parallel over t: tar = softmax(oh@Wtar^T + btar), dir likewise (3)
// ---------------------------------------------------------------------------
__global__ void phaseD(const float* __restrict__ oh_g,
                       const float* __restrict__ Wtar, const float* __restrict__ btar,
                       const float* __restrict__ Wdir, const float* __restrict__ bdir,
                       float* __restrict__ outp) {
  __shared__ float ohl[1024];
  const int t = blockIdx.x, tid = threadIdx.x;  // 64 threads
  for (int idx = tid; idx < 1024; idx += 64) ohl[idx] = oh_g[(size_t)t * 1024 + idx];
  __syncthreads();
  const int f = tid;
  for (int e = 0; e < E_; ++e) {
    float acc = btar[f];
    const float* wr = Wtar + f * 128;
    #pragma unroll 4
    for (int k = 0; k < 128; ++k) acc = fmaf(wr[k], ohl[e * 128 + k], acc);
    float m = acc;
    #pragma unroll
    for (int off = 32; off; off >>= 1) m = fmaxf(m, __shfl_xor(m, off, 64));
    float ex = __expf(acc - m);
    float s = ex;
    #pragma unroll
    for (int off = 32; off; off >>= 1) s += __shfl_xor(s, off, 64);
    outp[((size_t)t * 8 + e) * 64 + f] = ex / s;
  }
  if (tid < 8) {
    int e = tid;
    float d0 = bdir[0], d1 = bdir[1], d2 = bdir[2];
    #pragma unroll 4
    for (int k = 0; k < 128; ++k) {
      float x = ohl[e * 128 + k];
      d0 = fmaf(Wdir[k], x, d0);
      d1 = fmaf(Wdir[128 + k], x, d1);
      d2 = fmaf(Wdir[256 + k], x, d2);
    }
    float m = fmaxf(d0, fmaxf(d1, d2));
    float x0 = __expf(d0 - m), x1 = __expf(d1 - m), x2 = __expf(d2 - m);
    float s = x0 + x1 + x2;
    float* dp = outp + (size_t)T_ * 8 * 64 + ((size_t)t * 8 + e) * 3;
    dp[0] = x0 / s; dp[1] = x1 / s; dp[2] = x2 / s;
  }
}

extern "C" void kernel_launch(void* const* d_in, const int* in_sizes, int n_in,
                              void* d_out, int out_size, void* d_ws, size_t ws_size,
                              hipStream_t stream) {
  (void)in_sizes; (void)n_in; (void)out_size;
  const float* feat   = (const float*)d_in[0];
  const float* pre_h0 = (const float*)d_in[1];
  const float* pre_c0 = (const float*)d_in[2];
  const float* out_h0 = (const float*)d_in[3];
  const float* out_c0 = (const float*)d_in[4];
  const float* Wih_p0 = (const float*)d_in[5];
  const float* Whh_p0 = (const float*)d_in[6];
  const float* b_p0   = (const float*)d_in[7];
  const float* Wih_p1 = (const float*)d_in[8];
  const float* Whh_p1 = (const float*)d_in[9];
  const float* b_p1   = (const float*)d_in[10];
  const float* Wfc    = (const float*)d_in[11];
  const float* bfc    = (const float*)d_in[12];
  const float* Wih_c0 = (const float*)d_in[13];
  const float* Whh_c0 = (const float*)d_in[14];
  const float* b_c0   = (const float*)d_in[15];
  const float* Wih_c1 = (const float*)d_in[16];
  const float* Whh_c1 = (const float*)d_in[17];
  const float* b_c1   = (const float*)d_in[18];
  const float* Wih_o  = (const float*)d_in[19];
  const float* Whh_o  = (const float*)d_in[20];
  const float* b_o    = (const float*)d_in[21];
  const float* Wtar   = (const float*)d_in[22];
  const float* btar   = (const float*)d_in[23];
  const float* Wdir   = (const float*)d_in[24];
  const float* bdir   = (const float*)d_in[25];
  float* outp = (float*)d_out;

  // Workspace carve-up (fp32 words unless noted). Total ~86 MB; requires ws_size >= that.
  float* ws = (float*)d_ws;
  size_t off = 0;
  float* pre_outB = ws + off; off += (size_t)T_ * E_ * 128;   // 4 M
  float* opre1    = ws + off; off += (size_t)T_ * 512;        // 2 M
  float* oh_g     = ws + off; off += (size_t)T_ * E_ * 128;   // 4 M
  float* wt_p0    = ws + off; off += (size_t)448 * 1024;
  float* wt_p1    = ws + off; off += (size_t)512 * 1024;
  float* wt_c0    = ws + off; off += (size_t)256 * 512;
  float* wt_c1    = ws + off; off += (size_t)256 * 512;
  float* wt_o1    = ws + off; off += (size_t)256 * 512;
  float* wt_oh    = ws + off; off += (size_t)128 * 512;
  float* wt_o2    = ws + off; off += (size_t)192 * 512;
  float* hA       = ws + off; off += (size_t)2 * 2 * 8 * 256; // double-buffered h exchange
  __hip_bfloat16* opre2 = (__hip_bfloat16*)(ws + off);        // T*E*512 bf16 = 32 MB
  int* bars = (int*)((char*)d_ws + off * 4 + (size_t)T_ * E_ * 512 * 2);
  int* barA = bars;            // 2*T ints
  int* barC = bars + 2 * T_;   // T ints
  (void)ws_size;

  initK<<<dim3(512), dim3(256), 0, stream>>>(
      Wih_p0, Whh_p0, Wih_p1, Whh_p1, Wih_c0, Whh_c0, Wih_c1, Whh_c1, Wih_o, Whh_o,
      wt_p0, wt_p1, wt_c0, wt_c1, wt_o1, wt_oh, wt_o2, bars);
  opre2K<<<dim3(T_), dim3(256), 0, stream>>>(feat, wt_o2, opre2);
  phaseA<<<dim3(NA), dim3(256), 0, stream>>>(
      feat, pre_h0, pre_c0, wt_p0, wt_p1, b_p0, b_p1, Wfc, bfc, hA, pre_outB, barA);
  phaseB<<<dim3(T_ / 8), dim3(256), 0, stream>>>(
      pre_outB, wt_c0, wt_c1, b_c0, b_c1, wt_o1, b_o, opre1);
  phaseC<<<dim3(NC), dim3(256), 0, stream>>>(
      opre1, opre2, wt_oh, out_h0, out_c0, oh_g, barC);
  phaseD<<<dim3(T_), dim3(64), 0, stream>>>(oh_g, Wtar, btar, Wdir, bdir, outp);
}

// Round 2
// 55684.308 us; speedup vs baseline: 2.2521x; 2.2521x over previous
//
#include <hip/hip_runtime.h>
#include <hip/hip_bf16.h>

// Sizes from the reference
#define T_   4096
#define E_   8

__device__ __forceinline__ float sigm(float x)  { return 1.0f / (1.0f + __expf(-x)); }
__device__ __forceinline__ float tanh_(float x) { return 1.0f - 2.0f / (__expf(2.0f * x) + 1.0f); }

#define FMA_8(ACC, W, VA, VB)                                   \
  ACC[0] = fmaf((W), (VA).x, ACC[0]); ACC[1] = fmaf((W), (VA).y, ACC[1]); \
  ACC[2] = fmaf((W), (VA).z, ACC[2]); ACC[3] = fmaf((W), (VA).w, ACC[3]); \
  ACC[4] = fmaf((W), (VB).x, ACC[4]); ACC[5] = fmaf((W), (VB).y, ACC[5]); \
  ACC[6] = fmaf((W), (VB).z, ACC[6]); ACC[7] = fmaf((W), (VB).w, ACC[7]);

// ---------------------------------------------------------------------------
// initK: K-major weight copies + zero epochs.
// wt_p0[k][1024] k<192 = Wih_p0, else Whh_p0(k-192)
// wt_p1[k][1024] k<256 = Wih_p1, else Whh_p1
// wt_c0/wt_c1[k][512]; wt_o1[k][512]=Wih_o[:,k] (k<256); wt_o2[k][512]=Wih_o[:,256+k]
// ---------------------------------------------------------------------------
__global__ void initK(const float* __restrict__ Wih_p0, const float* __restrict__ Whh_p0,
                      const float* __restrict__ Wih_p1, const float* __restrict__ Whh_p1,
                      const float* __restrict__ Wih_c0, const float* __restrict__ Whh_c0,
                      const float* __restrict__ Wih_c1, const float* __restrict__ Whh_c1,
                      const float* __restrict__ Wih_o,
                      float* wt_p0, float* wt_p1, float* wt_c0, float* wt_c1,
                      float* wt_o1, float* wt_o2, int* epochs) {
  const int NTOT = 458752 + 524288 + 131072 + 131072 + 131072 + 98304 + 2048;
  for (int i = blockIdx.x * blockDim.x + threadIdx.x; i < NTOT; i += gridDim.x * blockDim.x) {
    int idx = i;
    if (idx < 458752) { int k = idx >> 10, g = idx & 1023;
      wt_p0[idx] = (k < 192) ? Wih_p0[g * 192 + k] : Whh_p0[g * 256 + (k - 192)]; continue; }
    idx -= 458752;
    if (idx < 524288) { int k = idx >> 10, g = idx & 1023;
      wt_p1[idx] = (k < 256) ? Wih_p1[g * 256 + k] : Whh_p1[g * 256 + (k - 256)]; continue; }
    idx -= 524288;
    if (idx < 131072) { int k = idx >> 9, r = idx & 511;
      wt_c0[idx] = (k < 128) ? Wih_c0[r * 128 + k] : Whh_c0[r * 128 + (k - 128)]; continue; }
    idx -= 131072;
    if (idx < 131072) { int k = idx >> 9, r = idx & 511;
      wt_c1[idx] = (k < 128) ? Wih_c1[r * 128 + k] : Whh_c1[r * 128 + (k - 128)]; continue; }
    idx -= 131072;
    if (idx < 131072) { int k = idx >> 9, r = idx & 511;
      wt_o1[idx] = Wih_o[r * 448 + k]; continue; }
    idx -= 131072;
    if (idx < 98304)  { int k = idx >> 9, r = idx & 511;
      wt_o2[idx] = Wih_o[r * 448 + 256 + k]; continue; }
    idx -= 98304;
    epochs[idx] = 0;
  }
}

// ---------------------------------------------------------------------------
// opre2K: parallel over t. opre2[t][e][512] = Wih_o[:,256:448] @ x(t,e)  (bf16)
// ---------------------------------------------------------------------------
__global__ void opre2K(const float* __restrict__ feat, const float* __restrict__ wt_o2,
                       __hip_bfloat16* __restrict__ opre2) {
  __shared__ float xb[192 * 8];
  const int t = blockIdx.x, tid = threadIdx.x;
  const float* ft = feat + (size_t)t * 640;
  for (int idx = tid; idx < 192 * 8; idx += 256) {
    int k = idx >> 3, e = idx & 7;
    xb[idx] = (k < 128) ? ft[k] : ft[128 + e * 64 + (k - 128)];
  }
  __syncthreads();
  const int r = tid;
  float A0[8] = {0,0,0,0,0,0,0,0};
  float A1[8] = {0,0,0,0,0,0,0,0};
  const float4* x4 = (const float4*)xb;
  #pragma unroll 2
  for (int k = 0; k < 192; ++k) {
    float w0 = wt_o2[k * 512 + r];
    float w1 = wt_o2[k * 512 + 256 + r];
    float4 a = x4[k * 2], b = x4[k * 2 + 1];
    FMA_8(A0, w0, a, b);
    FMA_8(A1, w1, a, b);
  }
  #pragma unroll
  for (int e = 0; e < 8; ++e) {
    opre2[((size_t)t * 8 + e) * 512 + r]       = __float2bfloat16(A0[e]);
    opre2[((size_t)t * 8 + e) * 512 + 256 + r] = __float2bfloat16(A1[e]);
  }
}

// ---------------------------------------------------------------------------
// phaseA: 32 WGs. WG 0-15 = G1 (layer0 chain), WG 16-31 = G2 (layer1 chain).
// G1 publishes h0all[t]; G2 consumes h0all, publishes h1all[t]. Relaxed-sc1
// protocol: atomic_exchange data (returns kept), s_waitcnt vmcnt(0), relaxed
// epoch store; consumers: relaxed epoch polls + relaxed sc1 data loads.
// NO acquire/release cache maintenance anywhere in the loop.
// ---------------------------------------------------------------------------
__launch_bounds__(256, 1)
__global__ void phaseA(const float* __restrict__ feat,
                       const float* __restrict__ pre_h0, const float* __restrict__ pre_c0,
                       const float* __restrict__ wt_p0, const float* __restrict__ wt_p1,
                       const float* __restrict__ b_p0, const float* __restrict__ b_p1,
                       float* __restrict__ h0all, float* __restrict__ h1all,
                       int* __restrict__ epochs) {
  __shared__ float xbuf[2][192 * 8];   // G1: x(t) ping-pong
  __shared__ float hself[256 * 8];     // G1: h0(t-1);  G2: h1(t-1)   [k][e]
  __shared__ float hin[2][256 * 8];    // G2: h0(t) ping-pong
  __shared__ float gl[4 * 64 * 8];
  const int wg = blockIdx.x, tid = threadIdx.x;
  const int r6 = tid & 63, kq = tid >> 6;
  const int ue = tid >> 4, uj = tid & 15;
  float sink = 0.f;

  if (wg < 16) {
    // ============================ G1: layer0 ============================
    const int col = ((r6 >> 4) << 8) + wg * 16 + (r6 & 15);
    const int j = wg * 16 + uj;
    float creg = 0.f, bi = 0.f, bff = 0.f, bg = 0.f, bo = 0.f;
    if (tid < 128) {
      creg = pre_c0[(ue * 2 + 0) * 256 + j];
      bi = b_p0[j]; bff = b_p0[256 + j]; bg = b_p0[512 + j]; bo = b_p0[768 + j];
    }
    for (int idx = tid; idx < 2048; idx += 256) {
      int k = idx >> 3, e = idx & 7;
      hself[idx] = pre_h0[(e * 2 + 0) * 256 + k];
    }
    for (int idx = tid; idx < 1536; idx += 256) {
      int k = idx >> 3, e = idx & 7;
      xbuf[0][idx] = (k < 128) ? feat[k] : feat[128 + e * 64 + (k - 128)];
    }
    __syncthreads();
    int xp = 0;
    for (int t = 0; t < T_; ++t) {
      float A[8] = {0,0,0,0,0,0,0,0};
      const float4* xx4 = (const float4*)xbuf[xp];
      const float4* hh4 = (const float4*)hself;
      const int kb = kq * 112, ke2 = kb + 112;
      const int xe = (ke2 < 192) ? ke2 : 192;
      #pragma unroll 4
      for (int k = kb; k < xe; ++k) {
        float w = wt_p0[k * 1024 + col];
        float4 a = xx4[k * 2], b = xx4[k * 2 + 1];
        FMA_8(A, w, a, b);
      }
      const int hb = (kb > 192) ? kb : 192;
      #pragma unroll 4
      for (int k = hb; k < ke2; ++k) {
        float w = wt_p0[k * 1024 + col];
        int kk = k - 192;
        float4 a = hh4[kk * 2], b = hh4[kk * 2 + 1];
        FMA_8(A, w, a, b);
      }
      float4* g4 = (float4*)gl;
      g4[(kq * 64 + r6) * 2]     = make_float4(A[0], A[1], A[2], A[3]);
      g4[(kq * 64 + r6) * 2 + 1] = make_float4(A[4], A[5], A[6], A[7]);
      // prefetch x(t+1) into regs (overlaps reduce + exchange)
      float px[6];
      if (t + 1 < T_) {
        const float* ft1 = feat + (size_t)(t + 1) * 640;
        #pragma unroll
        for (int i = 0; i < 6; ++i) {
          int idx = tid + i * 256; int k = idx >> 3, e = idx & 7;
          px[i] = (k < 128) ? ft1[k] : ft1[128 + e * 64 + (k - 128)];
        }
      }
      __syncthreads();
      if (tid < 128) {
        float s[4];
        #pragma unroll
        for (int g = 0; g < 4; ++g) {
          int rg = g * 16 + uj;
          s[g] = gl[(0 * 64 + rg) * 8 + ue] + gl[(1 * 64 + rg) * 8 + ue]
               + gl[(2 * 64 + rg) * 8 + ue] + gl[(3 * 64 + rg) * 8 + ue];
        }
        float c2 = sigm(s[1] + bff) * creg + sigm(s[0] + bi) * tanh_(s[2] + bg);
        float h2 = sigm(s[3] + bo) * tanh_(c2);
        creg = c2;
        sink += __hip_atomic_exchange(&h0all[(size_t)t * 2048 + j * 8 + ue], h2,
                                      __ATOMIC_RELAXED, __HIP_MEMORY_SCOPE_AGENT);
      }
      asm volatile("s_waitcnt vmcnt(0)" ::: "memory");
      __syncthreads();
      if (tid == 0)
        __hip_atomic_store(&epochs[wg * 32], t + 1, __ATOMIC_RELAXED, __HIP_MEMORY_SCOPE_AGENT);
      if (tid < 16) {
        while (__hip_atomic_load(&epochs[tid * 32], __ATOMIC_RELAXED, __HIP_MEMORY_SCOPE_AGENT) < t + 1)
          __builtin_amdgcn_s_sleep(1);
      }
      __syncthreads();
      asm volatile("" ::: "memory");
      if (t + 1 < T_) {
        #pragma unroll
        for (int i = 0; i < 6; ++i) xbuf[xp ^ 1][tid + i * 256] = px[i];
      }
      #pragma unroll
      for (int i = 0; i < 8; ++i) {
        int idx = tid + i * 256;
        hself[idx] = __hip_atomic_load(&h0all[(size_t)t * 2048 + idx],
                                       __ATOMIC_RELAXED, __HIP_MEMORY_SCOPE_AGENT);
      }
      __syncthreads();
      xp ^= 1;
    }
  } else {
    // ============================ G2: layer1 ============================
    const int wgl = wg - 16;
    const int col = ((r6 >> 4) << 8) + wgl * 16 + (r6 & 15);
    const int j = wgl * 16 + uj;
    float creg = 0.f, bi = 0.f, bff = 0.f, bg = 0.f, bo = 0.f;
    if (tid < 128) {
      creg = pre_c0[(ue * 2 + 1) * 256 + j];
      bi = b_p1[j]; bff = b_p1[256 + j]; bg = b_p1[512 + j]; bo = b_p1[768 + j];
    }
    for (int idx = tid; idx < 2048; idx += 256) {
      int k = idx >> 3, e = idx & 7;
      hself[idx] = pre_h0[(e * 2 + 1) * 256 + k];
    }
    __syncthreads();
    // wait for h0(0) and gather it
    if (tid < 16) {
      while (__hip_atomic_load(&epochs[tid * 32], __ATOMIC_RELAXED, __HIP_MEMORY_SCOPE_AGENT) < 1)
        __builtin_amdgcn_s_sleep(1);
    }
    __syncthreads();
    asm volatile("" ::: "memory");
    #pragma unroll
    for (int i = 0; i < 8; ++i) {
      int idx = tid + i * 256;
      hin[0][idx] = __hip_atomic_load(&h0all[idx], __ATOMIC_RELAXED, __HIP_MEMORY_SCOPE_AGENT);
    }
    __syncthreads();
    int hp = 0;
    for (int t = 0; t < T_; ++t) {
      float A[8] = {0,0,0,0,0,0,0,0};
      if (kq < 2) {
        const float4* h04 = (const float4*)hin[hp];
        const int kb = kq * 128, ke2 = kb + 128;
        #pragma unroll 4
        for (int k = kb; k < ke2; ++k) {
          float w = wt_p1[k * 1024 + col];
          float4 a = h04[k * 2], b = h04[k * 2 + 1];
          FMA_8(A, w, a, b);
        }
      } else {
        const float4* h14 = (const float4*)hself;
        const int kb = (kq - 2) * 128, ke2 = kb + 128;
        #pragma unroll 4
        for (int k = kb; k < ke2; ++k) {
          float w = wt_p1[(k + 256) * 1024 + col];
          float4 a = h14[k * 2], b = h14[k * 2 + 1];
          FMA_8(A, w, a, b);
        }
      }
      float4* g4 = (float4*)gl;
      g4[(kq * 64 + r6) * 2]     = make_float4(A[0], A[1], A[2], A[3]);
      g4[(kq * 64 + r6) * 2 + 1] = make_float4(A[4], A[5], A[6], A[7]);
      __syncthreads();
      if (tid < 128) {
        float s[4];
        #pragma unroll
        for (int g = 0; g < 4; ++g) {
          int rg = g * 16 + uj;
          s[g] = gl[(0 * 64 + rg) * 8 + ue] + gl[(1 * 64 + rg) * 8 + ue]
               + gl[(2 * 64 + rg) * 8 + ue] + gl[(3 * 64 + rg) * 8 + ue];
        }
        float c2 = sigm(s[1] + bff) * creg + sigm(s[0] + bi) * tanh_(s[2] + bg);
        float h2 = sigm(s[3] + bo) * tanh_(c2);
        creg = c2;
        sink += __hip_atomic_exchange(&h1all[(size_t)t * 2048 + j * 8 + ue], h2,
                                      __ATOMIC_RELAXED, __HIP_MEMORY_SCOPE_AGENT);
      }
      asm volatile("s_waitcnt vmcnt(0)" ::: "memory");
      __syncthreads();
      if (tid == 0)
        __hip_atomic_store(&epochs[(16 + wgl) * 32], t + 1, __ATOMIC_RELAXED, __HIP_MEMORY_SCOPE_AGENT);
      if (tid < 16) {
        if (t + 1 < T_) {
          while (__hip_atomic_load(&epochs[tid * 32], __ATOMIC_RELAXED, __HIP_MEMORY_SCOPE_AGENT) < t + 2)
            __builtin_amdgcn_s_sleep(1);
        }
      } else if (tid < 32) {
        while (__hip_atomic_load(&epochs[(16 + (tid - 16)) * 32], __ATOMIC_RELAXED, __HIP_MEMORY_SCOPE_AGENT) < t + 1)
          __builtin_amdgcn_s_sleep(1);
      }
      __syncthreads();
      asm volatile("" ::: "memory");
      if (t + 1 < T_) {
        #pragma unroll
        for (int i = 0; i < 8; ++i) {
          int idx = tid + i * 256;
          hin[hp ^ 1][idx] = __hip_atomic_load(&h0all[(size_t)(t + 1) * 2048 + idx],
                                               __ATOMIC_RELAXED, __HIP_MEMORY_SCOPE_AGENT);
        }
        #pragma unroll
        for (int i = 0; i < 8; ++i) {
          int idx = tid + i * 256;
          hself[idx] = __hip_atomic_load(&h1all[(size_t)t * 2048 + idx],
                                         __ATOMIC_RELAXED, __HIP_MEMORY_SCOPE_AGENT);
        }
      }
      __syncthreads();
      hp ^= 1;
    }
  }
  if (__float_as_uint(sink) == 0xDEADBEEFu) epochs[2047] = 1;  // keep exchange returns live
}

// ---------------------------------------------------------------------------
// fcK: parallel over t. pre_out[t][e][c] = leaky(Wfc @ h1all[t] + bfc)
// ---------------------------------------------------------------------------
__global__ void fcK(const float* __restrict__ h1all, const float* __restrict__ Wfc,
                    const float* __restrict__ bfc, float* __restrict__ pre_out) {
  __shared__ float hl[2048];
  const int t = blockIdx.x, tid = threadIdx.x;
  for (int idx = tid; idx < 2048; idx += 256) hl[idx] = h1all[(size_t)t * 2048 + idx];
  __syncthreads();
  const int c = tid >> 1, half = tid & 1;
  float b = bfc[c];
  float acc[4] = {b, b, b, b};
  const float4* h4 = (const float4*)hl;
  const float* wrow = Wfc + c * 256;
  #pragma unroll 4
  for (int k = 0; k < 256; ++k) {
    float w = wrow[k];
    float4 x = h4[k * 2 + half];
    acc[0] = fmaf(w, x.x, acc[0]); acc[1] = fmaf(w, x.y, acc[1]);
    acc[2] = fmaf(w, x.z, acc[2]); acc[3] = fmaf(w, x.w, acc[3]);
  }
  #pragma unroll
  for (int i = 0; i < 4; ++i) {
    int e = half * 4 + i;
    float v = acc[i];
    v = (v > 0.f) ? v : 0.05f * v;
    pre_out[((size_t)t * 8 + e) * 128 + c] = v;
  }
}

// ---------------------------------------------------------------------------
// comm cell for phase B (unchanged from r1)
// ---------------------------------------------------------------------------
__device__ __forceinline__ void comm_cell(
    const float* __restrict__ wt, const float* __restrict__ bias,
    const float* xin, float* hL, float* cL, float* glb, float* hout,
    float alpha, int tid) {
  const int r = tid;
  float A0[8] = {0,0,0,0,0,0,0,0};
  float A1[8] = {0,0,0,0,0,0,0,0};
  const float4* x4 = (const float4*)xin;
  #pragma unroll 2
  for (int k = 0; k < 128; ++k) {
    float w0 = wt[k * 512 + r];
    float w1 = wt[k * 512 + 256 + r];
    float4 a = x4[k * 2], b = x4[k * 2 + 1];
    FMA_8(A0, w0, a, b);
    FMA_8(A1, w1, a, b);
  }
  const float4* h4 = (const float4*)hL;
  #pragma unroll 2
  for (int k = 0; k < 128; ++k) {
    float w0 = wt[(128 + k) * 512 + r];
    float w1 = wt[(128 + k) * 512 + 256 + r];
    float4 a = h4[k * 2], b = h4[k * 2 + 1];
    FMA_8(A0, w0, a, b);
    FMA_8(A1, w1, a, b);
  }
  #pragma unroll
  for (int tt = 0; tt < 8; ++tt) { glb[r * 8 + tt] = A0[tt]; glb[(256 + r) * 8 + tt] = A1[tt]; }
  __syncthreads();
  for (int idx = tid; idx < 1024; idx += 256) {
    int jj = idx >> 3, tt = idx & 7;
    float gi = glb[jj * 8 + tt]         + bias[jj];
    float gf = glb[(128 + jj) * 8 + tt] + bias[128 + jj];
    float gg = glb[(256 + jj) * 8 + tt] + bias[256 + jj];
    float go = glb[(384 + jj) * 8 + tt] + bias[384 + jj];
    float cold = cL[idx], hold = hL[idx];
    float c2 = sigm(gf) * cold + sigm(gi) * tanh_(gg);
    float h2 = sigm(go) * tanh_(c2);
    float hb = fmaf(alpha, h2 - hold, hold);
    float cb = fmaf(alpha, c2 - cold, cold);
    hL[idx] = hb; cL[idx] = cb;
    if (hout) hout[idx] = hb;
  }
  __syncthreads();
}

// ---------------------------------------------------------------------------
// phaseB: parallel over t (8 timesteps / WG); emits opre1 (incl. b_o)
// ---------------------------------------------------------------------------
__launch_bounds__(256, 2)
__global__ void phaseB(const float* __restrict__ pre_out,
                       const float* __restrict__ wt_c0, const float* __restrict__ wt_c1,
                       const float* __restrict__ b_c0, const float* __restrict__ b_c1,
                       const float* __restrict__ wt_o1, const float* __restrict__ b_o,
                       float* __restrict__ opre1) {
  __shared__ float pol[128 * 8];
  __shared__ float ch0[128 * 8], cc0[128 * 8], ch1[128 * 8], cc1[128 * 8];
  __shared__ float h0b[128 * 8];
  __shared__ float glb[512 * 8];
  const int wg = blockIdx.x, tid = threadIdx.x;
  const int t0 = wg * 8;
  for (int idx = tid; idx < 1024; idx += 256) { ch0[idx]=0.f; cc0[idx]=0.f; ch1[idx]=0.f; cc1[idx]=0.f; }
  __syncthreads();
  float alpha = 1.0f;
  for (int rd = 0; rd < 3; ++rd) {
    for (int e = 0; e < E_; ++e) {
      for (int idx = tid; idx < 1024; idx += 256) {
        int tt = idx >> 7, k = idx & 127;
        pol[k * 8 + tt] = pre_out[(((size_t)(t0 + tt)) * 8 + e) * 128 + k];
      }
      __syncthreads();
      comm_cell(wt_c0, b_c0, pol, ch0, cc0, glb, h0b, alpha, tid);
      comm_cell(wt_c1, b_c1, h0b, ch1, cc1, glb, nullptr, alpha, tid);
    }
    alpha *= 0.333f;
  }
  {
    const int r = tid;
    float A0[8], A1[8];
    #pragma unroll
    for (int tt = 0; tt < 8; ++tt) { A0[tt] = b_o[r]; A1[tt] = b_o[256 + r]; }
    const float4* c04 = (const float4*)cc0;
    const float4* c14 = (const float4*)cc1;
    #pragma unroll 2
    for (int k = 0; k < 128; ++k) {
      float w0 = wt_o1[k * 512 + r], w1 = wt_o1[k * 512 + 256 + r];
      float4 a = c04[k * 2], b = c04[k * 2 + 1];
      FMA_8(A0, w0, a, b);
      FMA_8(A1, w1, a, b);
    }
    #pragma unroll 2
    for (int k = 0; k < 128; ++k) {
      float w0 = wt_o1[(128 + k) * 512 + r], w1 = wt_o1[(128 + k) * 512 + 256 + r];
      float4 a = c14[k * 2], b = c14[k * 2 + 1];
      FMA_8(A0, w0, a, b);
      FMA_8(A1, w1, a, b);
    }
    #pragma unroll
    for (int tt = 0; tt < 8; ++tt) {
      opre1[((size_t)(t0 + tt)) * 512 + r]       = A0[tt];
      opre1[((size_t)(t0 + tt)) * 512 + 256 + r] = A1[tt];
    }
  }
}

// ---------------------------------------------------------------------------
// phaseC: 8 WGs, one per ensemble e. No inter-WG sync. Whh_o lives in
// REGISTERS (2 rows/thread, fully unrolled). opre streams prefetched.
// ---------------------------------------------------------------------------
__launch_bounds__(256, 1)
__global__ void phaseC(const float* __restrict__ opre1, const __hip_bfloat16* __restrict__ opre2,
                       const float* __restrict__ Whh_o, const float* __restrict__ out_h0,
                       const float* __restrict__ out_c0, float* __restrict__ oh_g) {
  __shared__ float ohl[128];
  __shared__ float gl[512];
  const int e = blockIdx.x, tid = threadIdx.x;
  const int r0 = tid, r1 = tid + 256;
  float w0[128], w1[128];
  #pragma unroll
  for (int k = 0; k < 128; ++k) w0[k] = Whh_o[r0 * 128 + k];
  #pragma unroll
  for (int k = 0; k < 128; ++k) w1[k] = Whh_o[r1 * 128 + k];
  if (tid < 128) ohl[tid] = out_h0[e * 128 + tid];
  float creg = (tid < 128) ? out_c0[e * 128 + tid] : 0.f;
  __syncthreads();
  float p0a = opre1[r0], p0b = opre1[r1];
  float q0a = __bfloat162float(opre2[(size_t)e * 512 + r0]);
  float q0b = __bfloat162float(opre2[(size_t)e * 512 + r1]);
  for (int t = 0; t < T_; ++t) {
    float a0 = p0a + q0a, a1 = p0b + q0b;
    if (t + 1 < T_) {  // prefetch next step's opre terms
      p0a = opre1[(size_t)(t + 1) * 512 + r0];
      p0b = opre1[(size_t)(t + 1) * 512 + r1];
      q0a = __bfloat162float(opre2[((size_t)(t + 1) * 8 + e) * 512 + r0]);
      q0b = __bfloat162float(opre2[((size_t)(t + 1) * 8 + e) * 512 + r1]);
    }
    const float4* o4 = (const float4*)ohl;
    #pragma unroll
    for (int kk = 0; kk < 32; ++kk) {
      float4 x = o4[kk];
      a0 = fmaf(w0[kk * 4 + 0], x.x, a0); a0 = fmaf(w0[kk * 4 + 1], x.y, a0);
      a0 = fmaf(w0[kk * 4 + 2], x.z, a0); a0 = fmaf(w0[kk * 4 + 3], x.w, a0);
      a1 = fmaf(w1[kk * 4 + 0], x.x, a1); a1 = fmaf(w1[kk * 4 + 1], x.y, a1);
      a1 = fmaf(w1[kk * 4 + 2], x.z, a1); a1 = fmaf(w1[kk * 4 + 3], x.w, a1);
    }
    gl[r0] = a0; gl[r1] = a1;
    __syncthreads();
    if (tid < 128) {
      float gi = gl[tid], gf = gl[128 + tid], gg = gl[256 + tid], go = gl[384 + tid];
      float c2 = sigm(gf) * creg + sigm(gi) * tanh_(gg);
      float h2 = sigm(go) * tanh_(c2);
      creg = c2;
      ohl[tid] = h2;
      oh_g[(size_t)t * 1024 + e * 128 + tid] = h2;
    }
    __syncthreads();
  }
}

// ---------------------------------------------------------------------------
// phaseD: parallel over t: softmaxes (unchanged)
// ---------------------------------------------------------------------------
__global__ void phaseD(const float* __restrict__ oh_g,
                       const float* __restrict__ Wtar, const float* __restrict__ btar,
                       const float* __restrict__ Wdir, const float* __restrict__ bdir,
                       float* __restrict__ outp) {
  __shared__ float ohl[1024];
  const int t = blockIdx.x, tid = threadIdx.x;  // 64 threads
  for (int idx = tid; idx < 1024; idx += 64) ohl[idx] = oh_g[(size_t)t * 1024 + idx];
  __syncthreads();
  const int f = tid;
  for (int e = 0; e < E_; ++e) {
    float acc = btar[f];
    const float* wr = Wtar + f * 128;
    #pragma unroll 4
    for (int k = 0; k < 128; ++k) acc = fmaf(wr[k], ohl[e * 128 + k], acc);
    float m = acc;
    #pragma unroll
    for (int off = 32; off; off >>= 1) m = fmaxf(m, __shfl_xor(m, off, 64));
    float ex = __expf(acc - m);
    float s = ex;
    #pragma unroll
    for (int off = 32; off; off >>= 1) s += __shfl_xor(s, off, 64);
    outp[((size_t)t * 8 + e) * 64 + f] = ex / s;
  }
  if (tid < 8) {
    int e = tid;
    float d0 = bdir[0], d1 = bdir[1], d2 = bdir[2];
    #pragma unroll 4
    for (int k = 0; k < 128; ++k) {
      float x = ohl[e * 128 + k];
      d0 = fmaf(Wdir[k], x, d0);
      d1 = fmaf(Wdir[128 + k], x, d1);
      d2 = fmaf(Wdir[256 + k], x, d2);
    }
    float m = fmaxf(d0, fmaxf(d1, d2));
    float x0 = __expf(d0 - m), x1 = __expf(d1 - m), x2 = __expf(d2 - m);
    float s = x0 + x1 + x2;
    float* dp = outp + (size_t)T_ * 8 * 64 + ((size_t)t * 8 + e) * 3;
    dp[0] = x0 / s; dp[1] = x1 / s; dp[2] = x2 / s;
  }
}

extern "C" void kernel_launch(void* const* d_in, const int* in_sizes, int n_in,
                              void* d_out, int out_size, void* d_ws, size_t ws_size,
                              hipStream_t stream) {
  (void)in_sizes; (void)n_in; (void)out_size; (void)ws_size;
  const float* feat   = (const float*)d_in[0];
  const float* pre_h0 = (const float*)d_in[1];
  const float* pre_c0 = (const float*)d_in[2];
  const float* out_h0 = (const float*)d_in[3];
  const float* out_c0 = (const float*)d_in[4];
  const float* Wih_p0 = (const float*)d_in[5];
  const float* Whh_p0 = (const float*)d_in[6];
  const float* b_p0   = (const float*)d_in[7];
  const float* Wih_p1 = (const float*)d_in[8];
  const float* Whh_p1 = (const float*)d_in[9];
  const float* b_p1   = (const float*)d_in[10];
  const float* Wfc    = (const float*)d_in[11];
  const float* bfc    = (const float*)d_in[12];
  const float* Wih_c0 = (const float*)d_in[13];
  const float* Whh_c0 = (const float*)d_in[14];
  const float* b_c0   = (const float*)d_in[15];
  const float* Wih_c1 = (const float*)d_in[16];
  const float* Whh_c1 = (const float*)d_in[17];
  const float* b_c1   = (const float*)d_in[18];
  const float* Wih_o  = (const float*)d_in[19];
  const float* Whh_o  = (const float*)d_in[20];
  const float* b_o    = (const float*)d_in[21];
  const float* Wtar   = (const float*)d_in[22];
  const float* btar   = (const float*)d_in[23];
  const float* Wdir   = (const float*)d_in[24];
  const float* bdir   = (const float*)d_in[25];
  float* outp = (float*)d_out;

  // Workspace carve-up (fp32 words). Total ~148 MB.
  float* ws = (float*)d_ws;
  size_t off = 0;
  float* pre_outB = ws + off; off += (size_t)T_ * E_ * 128;   // 4.19 M
  float* opre1    = ws + off; off += (size_t)T_ * 512;        // 2.10 M
  float* oh_g     = ws + off; off += (size_t)T_ * E_ * 128;   // 4.19 M
  float* wt_p0    = ws + off; off += (size_t)448 * 1024;
  float* wt_p1    = ws + off; off += (size_t)512 * 1024;
  float* wt_c0    = ws + off; off += (size_t)256 * 512;
  float* wt_c1    = ws + off; off += (size_t)256 * 512;
  float* wt_o1    = ws + off; off += (size_t)256 * 512;
  float* wt_o2    = ws + off; off += (size_t)192 * 512;
  float* h0all    = ws + off; off += (size_t)T_ * 2048;       // 8.39 M
  float* h1all    = ws + off; off += (size_t)T_ * 2048;       // 8.39 M
  __hip_bfloat16* opre2 = (__hip_bfloat16*)(ws + off);        // T*8*512 bf16
  off += (size_t)T_ * E_ * 512 / 2;
  int* epochs = (int*)(ws + off);                             // 2048 ints

  initK<<<dim3(512), dim3(256), 0, stream>>>(
      Wih_p0, Whh_p0, Wih_p1, Whh_p1, Wih_c0, Whh_c0, Wih_c1, Whh_c1, Wih_o,
      wt_p0, wt_p1, wt_c0, wt_c1, wt_o1, wt_o2, epochs);
  opre2K<<<dim3(T_), dim3(256), 0, stream>>>(feat, wt_o2, opre2);
  phaseA<<<dim3(32), dim3(256), 0, stream>>>(
      feat, pre_h0, pre_c0, wt_p0, wt_p1, b_p0, b_p1, h0all, h1all, epochs);
  fcK<<<dim3(T_), dim3(256), 0, stream>>>(h1all, Wfc, bfc, pre_outB);
  phaseB<<<dim3(T_ / 8), dim3(256), 0, stream>>>(
      pre_outB, wt_c0, wt_c1, b_c0, b_c1, wt_o1, b_o, opre1);
  phaseC<<<dim3(E_), dim3(256), 0, stream>>>(
      opre1, opre2, Whh_o, out_h0, out_c0, oh_g);
  phaseD<<<dim3(T_), dim3(64), 0, stream>>>(oh_g, Wtar, btar, Wdir, bdir, outp);
}

// Round 3
// 37856.802 us; speedup vs baseline: 3.3127x; 1.4709x over previous
//
#include <hip/hip_runtime.h>
#include <hip/hip_bf16.h>

// Sizes from the reference
#define T_   4096
#define E_   8

typedef unsigned long long ull;

__device__ __forceinline__ float sigm(float x)  { return 1.0f / (1.0f + __expf(-x)); }
__device__ __forceinline__ float tanh_(float x) { return 1.0f - 2.0f / (__expf(2.0f * x) + 1.0f); }

__device__ __forceinline__ void waitCnt(int* p, int target) {
  while (__hip_atomic_load(p, __ATOMIC_RELAXED, __HIP_MEMORY_SCOPE_AGENT) < target)
    __builtin_amdgcn_s_sleep(1);
}

#define FMA_8(ACC, W, VA, VB)                                   \
  ACC[0] = fmaf((W), (VA).x, ACC[0]); ACC[1] = fmaf((W), (VA).y, ACC[1]); \
  ACC[2] = fmaf((W), (VA).z, ACC[2]); ACC[3] = fmaf((W), (VA).w, ACC[3]); \
  ACC[4] = fmaf((W), (VB).x, ACC[4]); ACC[5] = fmaf((W), (VB).y, ACC[5]); \
  ACC[6] = fmaf((W), (VB).z, ACC[6]); ACC[7] = fmaf((W), (VB).w, ACC[7]);

// ---------------------------------------------------------------------------
// initK: K-major weight copies + zero barrier counters.
// wt_p0 PACKED: [k][c] c = wg*64 + gate*16 + jl  (orig col = gate*256+wg*16+jl)
//   k<192 = Wih_p0, else Whh_p0(k-192).  wt_p1 same packing, k<256 ih else hh.
// wt_c0/wt_c1[k][512]; wt_o1[k][512]=Wih_o[:,k] (k<256); wt_o2[k][512]=Wih_o[:,256+k]
// ---------------------------------------------------------------------------
__global__ void initK(const float* __restrict__ Wih_p0, const float* __restrict__ Whh_p0,
                      const float* __restrict__ Wih_p1, const float* __restrict__ Whh_p1,
                      const float* __restrict__ Wih_c0, const float* __restrict__ Whh_c0,
                      const float* __restrict__ Wih_c1, const float* __restrict__ Whh_c1,
                      const float* __restrict__ Wih_o,
                      float* wt_p0, float* wt_p1, float* wt_c0, float* wt_c1,
                      float* wt_o1, float* wt_o2, int* bars) {
  const int NTOT = 458752 + 524288 + 131072 + 131072 + 131072 + 98304 + 131072;
  for (int i = blockIdx.x * blockDim.x + threadIdx.x; i < NTOT; i += gridDim.x * blockDim.x) {
    int idx = i;
    if (idx < 458752) { int k = idx >> 10, c = idx & 1023;
      int wg = c >> 6, r6 = c & 63, gate = r6 >> 4, jl = r6 & 15;
      int col = gate * 256 + wg * 16 + jl;
      wt_p0[idx] = (k < 192) ? Wih_p0[col * 192 + k] : Whh_p0[col * 256 + (k - 192)]; continue; }
    idx -= 458752;
    if (idx < 524288) { int k = idx >> 10, c = idx & 1023;
      int wg = c >> 6, r6 = c & 63, gate = r6 >> 4, jl = r6 & 15;
      int col = gate * 256 + wg * 16 + jl;
      wt_p1[idx] = (k < 256) ? Wih_p1[col * 256 + k] : Whh_p1[col * 256 + (k - 256)]; continue; }
    idx -= 524288;
    if (idx < 131072) { int k = idx >> 9, r = idx & 511;
      wt_c0[idx] = (k < 128) ? Wih_c0[r * 128 + k] : Whh_c0[r * 128 + (k - 128)]; continue; }
    idx -= 131072;
    if (idx < 131072) { int k = idx >> 9, r = idx & 511;
      wt_c1[idx] = (k < 128) ? Wih_c1[r * 128 + k] : Whh_c1[r * 128 + (k - 128)]; continue; }
    idx -= 131072;
    if (idx < 131072) { int k = idx >> 9, r = idx & 511;
      wt_o1[idx] = Wih_o[r * 448 + k]; continue; }
    idx -= 131072;
    if (idx < 98304)  { int k = idx >> 9, r = idx & 511;
      wt_o2[idx] = Wih_o[r * 448 + 256 + k]; continue; }
    idx -= 98304;
    bars[idx] = 0;
  }
}

// ---------------------------------------------------------------------------
// opre2K: parallel over t. opre2[t][e][512] = Wih_o[:,256:448] @ x(t,e)  (bf16)
// ---------------------------------------------------------------------------
__global__ void opre2K(const float* __restrict__ feat, const float* __restrict__ wt_o2,
                       __hip_bfloat16* __restrict__ opre2) {
  __shared__ float xb[192 * 8];
  const int t = blockIdx.x, tid = threadIdx.x;
  const float* ft = feat + (size_t)t * 640;
  for (int idx = tid; idx < 192 * 8; idx += 256) {
    int k = idx >> 3, e = idx & 7;
    xb[idx] = (k < 128) ? ft[k] : ft[128 + e * 64 + (k - 128)];
  }
  __syncthreads();
  const int r = tid;
  float A0[8] = {0,0,0,0,0,0,0,0};
  float A1[8] = {0,0,0,0,0,0,0,0};
  const float4* x4 = (const float4*)xb;
  #pragma unroll 2
  for (int k = 0; k < 192; ++k) {
    float w0 = wt_o2[k * 512 + r];
    float w1 = wt_o2[k * 512 + 256 + r];
    float4 a = x4[k * 2], b = x4[k * 2 + 1];
    FMA_8(A0, w0, a, b);
    FMA_8(A1, w1, a, b);
  }
  #pragma unroll
  for (int e = 0; e < 8; ++e) {
    opre2[((size_t)t * 8 + e) * 512 + r]       = __float2bfloat16(A0[e]);
    opre2[((size_t)t * 8 + e) * 512 + 256 + r] = __float2bfloat16(A1[e]);
  }
}

// ---------------------------------------------------------------------------
// phaseA: 32 WGs. WG 0-15 = G1 (layer0), WG 16-31 = G2 (layer1, one step
// behind). Publish = relaxed atomic b32 stores (sc1 write-through), drained
// by __syncthreads' vmcnt(0); one fetch_add per WG per step on a per-step
// counter; gather = b64 relaxed atomic loads. The x-part (no h dependency)
// of step t+1 is computed between publish and poll to hide sync latency.
// ---------------------------------------------------------------------------
__launch_bounds__(256, 1)
__global__ void phaseA(const float* __restrict__ feat,
                       const float* __restrict__ pre_h0, const float* __restrict__ pre_c0,
                       const float* __restrict__ wt_p0, const float* __restrict__ wt_p1,
                       const float* __restrict__ b_p0, const float* __restrict__ b_p1,
                       float* __restrict__ h0all, float* __restrict__ h1all,
                       int* __restrict__ barsA, int* __restrict__ barsB) {
  __shared__ float xbuf[2048];   // G1: x(t) [1536]; G2: h0(t) [2048]
  __shared__ float hself[2048];  // h(t-1) of own layer, [k][e]
  __shared__ float gl[2048];     // partial sums [kq][64][8]
  const int wg = blockIdx.x, tid = threadIdx.x;
  const int r6 = tid & 63, kq = tid >> 6;
  const int uj = tid >> 3, ue = tid & 7;   // reduce-thread map (tid<128)

  if (wg < 16) {
    // ============================ G1: layer0 ============================
    const float* wp = wt_p0 + wg * 64 + r6;
    const int j = wg * 16 + uj;
    float creg = 0.f, bi = 0.f, bff = 0.f, bg = 0.f, bo = 0.f;
    if (tid < 128) {
      creg = pre_c0[(ue * 2 + 0) * 256 + j];
      bi = b_p0[j]; bff = b_p0[256 + j]; bg = b_p0[512 + j]; bo = b_p0[768 + j];
    }
    for (int idx = tid; idx < 2048; idx += 256) {
      int k = idx >> 3, e = idx & 7;
      hself[idx] = pre_h0[(e * 2 + 0) * 256 + k];
    }
    for (int idx = tid; idx < 1536; idx += 256) {
      int k = idx >> 3, e = idx & 7;
      xbuf[idx] = (k < 128) ? feat[k] : feat[128 + e * 64 + (k - 128)];
    }
    __syncthreads();
    float Ax[8] = {0,0,0,0,0,0,0,0};
    {
      const float4* x4 = (const float4*)xbuf;
      #pragma unroll 8
      for (int k = kq * 48; k < kq * 48 + 48; ++k) {
        float w = wp[k * 1024];
        float4 a = x4[k * 2], b = x4[k * 2 + 1];
        FMA_8(Ax, w, a, b);
      }
    }
    for (int t = 0; t < T_; ++t) {
      float A[8];
      #pragma unroll
      for (int i = 0; i < 8; ++i) A[i] = Ax[i];
      {  // h-part: k in [192+kq*64, 192+kq*64+64)
        const float4* h4 = (const float4*)hself;
        const int kb = 192 + kq * 64;
        #pragma unroll 8
        for (int k = kb; k < kb + 64; ++k) {
          float w = wp[k * 1024];
          int kk = k - 192;
          float4 a = h4[kk * 2], b = h4[kk * 2 + 1];
          FMA_8(A, w, a, b);
        }
      }
      float px[6];
      if (t + 1 < T_) {
        const float* ft1 = feat + (size_t)(t + 1) * 640;
        #pragma unroll
        for (int i = 0; i < 6; ++i) {
          int idx = tid + i * 256; int k = idx >> 3, e = idx & 7;
          px[i] = (k < 128) ? ft1[k] : ft1[128 + e * 64 + (k - 128)];
        }
      }
      {
        float4* g4 = (float4*)gl;
        g4[(kq * 64 + r6) * 2]     = make_float4(A[0], A[1], A[2], A[3]);
        g4[(kq * 64 + r6) * 2 + 1] = make_float4(A[4], A[5], A[6], A[7]);
      }
      __syncthreads();                               // (a) gl ready
      if (tid < 128) {
        float s0 = 0.f, s1 = 0.f, s2 = 0.f, s3 = 0.f;
        #pragma unroll
        for (int q = 0; q < 4; ++q) {
          s0 += gl[q * 512 + tid];       s1 += gl[q * 512 + 128 + tid];
          s2 += gl[q * 512 + 256 + tid]; s3 += gl[q * 512 + 384 + tid];
        }
        float c2 = sigm(s1 + bff) * creg + sigm(s0 + bi) * tanh_(s2 + bg);
        float h2 = sigm(s3 + bo) * tanh_(c2);
        creg = c2;
        __hip_atomic_store(&h0all[(size_t)t * 2048 + wg * 128 + tid], h2,
                           __ATOMIC_RELAXED, __HIP_MEMORY_SCOPE_AGENT);
      }
      __syncthreads();                               // (b) drains stores (vmcnt0)
      if (tid == 0)
        __hip_atomic_fetch_add(&barsA[t * 16], 1, __ATOMIC_RELAXED, __HIP_MEMORY_SCOPE_AGENT);
      if (t + 1 < T_) {
        #pragma unroll
        for (int i = 0; i < 6; ++i) xbuf[tid + i * 256] = px[i];
      }
      __syncthreads();                               // (c) xbuf = x(t+1)
      if (t + 1 < T_) {                              // x-part of t+1 (sync shadow)
        #pragma unroll
        for (int i = 0; i < 8; ++i) Ax[i] = 0.f;
        const float4* x4 = (const float4*)xbuf;
        #pragma unroll 8
        for (int k = kq * 48; k < kq * 48 + 48; ++k) {
          float w = wp[k * 1024];
          float4 a = x4[k * 2], b = x4[k * 2 + 1];
          FMA_8(Ax, w, a, b);
        }
      }
      if (tid == 0) waitCnt(&barsA[t * 16], 16);
      __syncthreads();                               // (d) barrier passed
      if (t + 1 < T_) {
        const ull* s8 = (const ull*)(h0all + (size_t)t * 2048);
        ull* d8 = (ull*)hself;
        #pragma unroll
        for (int i = 0; i < 4; ++i)
          d8[tid * 4 + i] = __hip_atomic_load(&s8[tid * 4 + i],
                                              __ATOMIC_RELAXED, __HIP_MEMORY_SCOPE_AGENT);
      }
      __syncthreads();                               // (e) hself = h0(t)
    }
  } else {
    // ============================ G2: layer1 ============================
    const int wgl = wg - 16;
    const float* wp = wt_p1 + wgl * 64 + r6;
    const int j = wgl * 16 + uj;
    float creg = 0.f, bi = 0.f, bff = 0.f, bg = 0.f, bo = 0.f;
    if (tid < 128) {
      creg = pre_c0[(ue * 2 + 1) * 256 + j];
      bi = b_p1[j]; bff = b_p1[256 + j]; bg = b_p1[512 + j]; bo = b_p1[768 + j];
    }
    for (int idx = tid; idx < 2048; idx += 256) {
      int k = idx >> 3, e = idx & 7;
      hself[idx] = pre_h0[(e * 2 + 1) * 256 + k];
    }
    __syncthreads();
    if (tid == 0) waitCnt(&barsA[0], 16);
    __syncthreads();
    {
      const ull* s8 = (const ull*)h0all;
      ull* d8 = (ull*)xbuf;
      #pragma unroll
      for (int i = 0; i < 4; ++i)
        d8[tid * 4 + i] = __hip_atomic_load(&s8[tid * 4 + i],
                                            __ATOMIC_RELAXED, __HIP_MEMORY_SCOPE_AGENT);
    }
    __syncthreads();
    float Ax[8] = {0,0,0,0,0,0,0,0};
    {
      const float4* x4 = (const float4*)xbuf;
      #pragma unroll 8
      for (int k = kq * 64; k < kq * 64 + 64; ++k) {
        float w = wp[k * 1024];
        float4 a = x4[k * 2], b = x4[k * 2 + 1];
        FMA_8(Ax, w, a, b);
      }
    }
    for (int t = 0; t < T_; ++t) {
      float A[8];
      #pragma unroll
      for (int i = 0; i < 8; ++i) A[i] = Ax[i];
      {  // h-part: k in [256+kq*64, ...+64)
        const float4* h4 = (const float4*)hself;
        const int kb = 256 + kq * 64;
        #pragma unroll 8
        for (int k = kb; k < kb + 64; ++k) {
          float w = wp[k * 1024];
          int kk = k - 256;
          float4 a = h4[kk * 2], b = h4[kk * 2 + 1];
          FMA_8(A, w, a, b);
        }
      }
      {
        float4* g4 = (float4*)gl;
        g4[(kq * 64 + r6) * 2]     = make_float4(A[0], A[1], A[2], A[3]);
        g4[(kq * 64 + r6) * 2 + 1] = make_float4(A[4], A[5], A[6], A[7]);
      }
      __syncthreads();                               // (a)
      if (tid < 128) {
        float s0 = 0.f, s1 = 0.f, s2 = 0.f, s3 = 0.f;
        #pragma unroll
        for (int q = 0; q < 4; ++q) {
          s0 += gl[q * 512 + tid];       s1 += gl[q * 512 + 128 + tid];
          s2 += gl[q * 512 + 256 + tid]; s3 += gl[q * 512 + 384 + tid];
        }
        float c2 = sigm(s1 + bff) * creg + sigm(s0 + bi) * tanh_(s2 + bg);
        float h2 = sigm(s3 + bo) * tanh_(c2);
        creg = c2;
        __hip_atomic_store(&h1all[(size_t)t * 2048 + wgl * 128 + tid], h2,
                           __ATOMIC_RELAXED, __HIP_MEMORY_SCOPE_AGENT);
      }
      __syncthreads();                               // (b) drain
      if (tid == 0)
        __hip_atomic_fetch_add(&barsB[t * 16], 1, __ATOMIC_RELAXED, __HIP_MEMORY_SCOPE_AGENT);
      if (t + 1 < T_) {
        if (tid == 0)  waitCnt(&barsA[(t + 1) * 16], 16);   // h0(t+1) ready
        if (tid == 64) waitCnt(&barsB[t * 16], 16);         // h1(t) ready
      }
      __syncthreads();                               // (c)
      if (t + 1 < T_) {
        const ull* s0p = (const ull*)(h0all + (size_t)(t + 1) * 2048);
        const ull* s1p = (const ull*)(h1all + (size_t)t * 2048);
        ull v0[4], v1[4];
        #pragma unroll
        for (int i = 0; i < 4; ++i)
          v0[i] = __hip_atomic_load(&s0p[tid * 4 + i], __ATOMIC_RELAXED, __HIP_MEMORY_SCOPE_AGENT);
        #pragma unroll
        for (int i = 0; i < 4; ++i)
          v1[i] = __hip_atomic_load(&s1p[tid * 4 + i], __ATOMIC_RELAXED, __HIP_MEMORY_SCOPE_AGENT);
        ull* d0 = (ull*)xbuf; ull* d1 = (ull*)hself;
        #pragma unroll
        for (int i = 0; i < 4; ++i) { d0[tid * 4 + i] = v0[i]; d1[tid * 4 + i] = v1[i]; }
      }
      __syncthreads();                               // (d)
      if (t + 1 < T_) {                              // h0-part of t+1 (sync shadow-ish)
        #pragma unroll
        for (int i = 0; i < 8; ++i) Ax[i] = 0.f;
        const float4* x4 = (const float4*)xbuf;
        #pragma unroll 8
        for (int k = kq * 64; k < kq * 64 + 64; ++k) {
          float w = wp[k * 1024];
          float4 a = x4[k * 2], b = x4[k * 2 + 1];
          FMA_8(Ax, w, a, b);
        }
      }
    }
  }
}

// ---------------------------------------------------------------------------
// fcK: parallel over t. pre_out[t][e][c] = leaky(Wfc @ h1all[t] + bfc)
// h1all layout: [t][j*8+e]  (j = h index, e = ensemble)
// ---------------------------------------------------------------------------
__global__ void fcK(const float* __restrict__ h1all, const float* __restrict__ Wfc,
                    const float* __restrict__ bfc, float* __restrict__ pre_out) {
  __shared__ float hl[2048];
  const int t = blockIdx.x, tid = threadIdx.x;
  for (int idx = tid; idx < 2048; idx += 256) hl[idx] = h1all[(size_t)t * 2048 + idx];
  __syncthreads();
  const int c = tid >> 1, half = tid & 1;
  float b = bfc[c];
  float acc[4] = {b, b, b, b};
  const float4* h4 = (const float4*)hl;
  const float* wrow = Wfc + c * 256;
  #pragma unroll 4
  for (int k = 0; k < 256; ++k) {
    float w = wrow[k];
    float4 x = h4[k * 2 + half];
    acc[0] = fmaf(w, x.x, acc[0]); acc[1] = fmaf(w, x.y, acc[1]);
    acc[2] = fmaf(w, x.z, acc[2]); acc[3] = fmaf(w, x.w, acc[3]);
  }
  #pragma unroll
  for (int i = 0; i < 4; ++i) {
    int e = half * 4 + i;
    float v = acc[i];
    v = (v > 0.f) ? v : 0.05f * v;
    pre_out[((size_t)t * 8 + e) * 128 + c] = v;
  }
}

// ---------------------------------------------------------------------------
// comm cell for phase B
// ---------------------------------------------------------------------------
__device__ __forceinline__ void comm_cell(
    const float* __restrict__ wt, const float* __restrict__ bias,
    const float* xin, float* hL, float* cL, float* glb, float* hout,
    float alpha, int tid) {
  const int r = tid;
  float A0[8] = {0,0,0,0,0,0,0,0};
  float A1[8] = {0,0,0,0,0,0,0,0};
  const float4* x4 = (const float4*)xin;
  #pragma unroll 2
  for (int k = 0; k < 128; ++k) {
    float w0 = wt[k * 512 + r];
    float w1 = wt[k * 512 + 256 + r];
    float4 a = x4[k * 2], b = x4[k * 2 + 1];
    FMA_8(A0, w0, a, b);
    FMA_8(A1, w1, a, b);
  }
  const float4* h4 = (const float4*)hL;
  #pragma unroll 2
  for (int k = 0; k < 128; ++k) {
    float w0 = wt[(128 + k) * 512 + r];
    float w1 = wt[(128 + k) * 512 + 256 + r];
    float4 a = h4[k * 2], b = h4[k * 2 + 1];
    FMA_8(A0, w0, a, b);
    FMA_8(A1, w1, a, b);
  }
  #pragma unroll
  for (int tt = 0; tt < 8; ++tt) { glb[r * 8 + tt] = A0[tt]; glb[(256 + r) * 8 + tt] = A1[tt]; }
  __syncthreads();
  for (int idx = tid; idx < 1024; idx += 256) {
    int jj = idx >> 3, tt = idx & 7;
    float gi = glb[jj * 8 + tt]         + bias[jj];
    float gf = glb[(128 + jj) * 8 + tt] + bias[128 + jj];
    float gg = glb[(256 + jj) * 8 + tt] + bias[256 + jj];
    float go = glb[(384 + jj) * 8 + tt] + bias[384 + jj];
    float cold = cL[idx], hold = hL[idx];
    float c2 = sigm(gf) * cold + sigm(gi) * tanh_(gg);
    float h2 = sigm(go) * tanh_(c2);
    float hb = fmaf(alpha, h2 - hold, hold);
    float cb = fmaf(alpha, c2 - cold, cold);
    hL[idx] = hb; cL[idx] = cb;
    if (hout) hout[idx] = hb;
  }
  __syncthreads();
}

// ---------------------------------------------------------------------------
// phaseB: parallel over t (8 timesteps / WG); emits opre1 (incl. b_o)
// ---------------------------------------------------------------------------
__launch_bounds__(256, 2)
__global__ void phaseB(const float* __restrict__ pre_out,
                       const float* __restrict__ wt_c0, const float* __restrict__ wt_c1,
                       const float* __restrict__ b_c0, const float* __restrict__ b_c1,
                       const float* __restrict__ wt_o1, const float* __restrict__ b_o,
                       float* __restrict__ opre1) {
  __shared__ float pol[128 * 8];
  __shared__ float ch0[128 * 8], cc0[128 * 8], ch1[128 * 8], cc1[128 * 8];
  __shared__ float h0b[128 * 8];
  __shared__ float glb[512 * 8];
  const int wg = blockIdx.x, tid = threadIdx.x;
  const int t0 = wg * 8;
  for (int idx = tid; idx < 1024; idx += 256) { ch0[idx]=0.f; cc0[idx]=0.f; ch1[idx]=0.f; cc1[idx]=0.f; }
  __syncthreads();
  float alpha = 1.0f;
  for (int rd = 0; rd < 3; ++rd) {
    for (int e = 0; e < E_; ++e) {
      for (int idx = tid; idx < 1024; idx += 256) {
        int tt = idx >> 7, k = idx & 127;
        pol[k * 8 + tt] = pre_out[(((size_t)(t0 + tt)) * 8 + e) * 128 + k];
      }
      __syncthreads();
      comm_cell(wt_c0, b_c0, pol, ch0, cc0, glb, h0b, alpha, tid);
      comm_cell(wt_c1, b_c1, h0b, ch1, cc1, glb, nullptr, alpha, tid);
    }
    alpha *= 0.333f;
  }
  {
    const int r = tid;
    float A0[8], A1[8];
    #pragma unroll
    for (int tt = 0; tt < 8; ++tt) { A0[tt] = b_o[r]; A1[tt] = b_o[256 + r]; }
    const float4* c04 = (const float4*)cc0;
    const float4* c14 = (const float4*)cc1;
    #pragma unroll 2
    for (int k = 0; k < 128; ++k) {
      float w0 = wt_o1[k * 512 + r], w1 = wt_o1[k * 512 + 256 + r];
      float4 a = c04[k * 2], b = c04[k * 2 + 1];
      FMA_8(A0, w0, a, b);
      FMA_8(A1, w1, a, b);
    }
    #pragma unroll 2
    for (int k = 0; k < 128; ++k) {
      float w0 = wt_o1[(128 + k) * 512 + r], w1 = wt_o1[(128 + k) * 512 + 256 + r];
      float4 a = c14[k * 2], b = c14[k * 2 + 1];
      FMA_8(A0, w0, a, b);
      FMA_8(A1, w1, a, b);
    }
    #pragma unroll
    for (int tt = 0; tt < 8; ++tt) {
      opre1[((size_t)(t0 + tt)) * 512 + r]       = A0[tt];
      opre1[((size_t)(t0 + tt)) * 512 + 256 + r] = A1[tt];
    }
  }
}

// ---------------------------------------------------------------------------
// phaseC: 8 WGs, one per ensemble e. No inter-WG sync; Whh_o in registers.
// ---------------------------------------------------------------------------
__launch_bounds__(256, 1)
__global__ void phaseC(const float* __restrict__ opre1, const __hip_bfloat16* __restrict__ opre2,
                       const float* __restrict__ Whh_o, const float* __restrict__ out_h0,
                       const float* __restrict__ out_c0, float* __restrict__ oh_g) {
  __shared__ float ohl[128];
  __shared__ float gl[512];
  const int e = blockIdx.x, tid = threadIdx.x;
  const int r0 = tid, r1 = tid + 256;
  float w0[128], w1[128];
  #pragma unroll
  for (int k = 0; k < 128; ++k) w0[k] = Whh_o[r0 * 128 + k];
  #pragma unroll
  for (int k = 0; k < 128; ++k) w1[k] = Whh_o[r1 * 128 + k];
  if (tid < 128) ohl[tid] = out_h0[e * 128 + tid];
  float creg = (tid < 128) ? out_c0[e * 128 + tid] : 0.f;
  __syncthreads();
  float p0a = opre1[r0], p0b = opre1[r1];
  float q0a = __bfloat162float(opre2[(size_t)e * 512 + r0]);
  float q0b = __bfloat162float(opre2[(size_t)e * 512 + r1]);
  for (int t = 0; t < T_; ++t) {
    float a0 = p0a + q0a, a1 = p0b + q0b;
    if (t + 1 < T_) {
      p0a = opre1[(size_t)(t + 1) * 512 + r0];
      p0b = opre1[(size_t)(t + 1) * 512 + r1];
      q0a = __bfloat162float(opre2[((size_t)(t + 1) * 8 + e) * 512 + r0]);
      q0b = __bfloat162float(opre2[((size_t)(t + 1) * 8 + e) * 512 + r1]);
    }
    const float4* o4 = (const float4*)ohl;
    #pragma unroll
    for (int kk = 0; kk < 32; ++kk) {
      float4 x = o4[kk];
      a0 = fmaf(w0[kk * 4 + 0], x.x, a0); a0 = fmaf(w0[kk * 4 + 1], x.y, a0);
      a0 = fmaf(w0[kk * 4 + 2], x.z, a0); a0 = fmaf(w0[kk * 4 + 3], x.w, a0);
      a1 = fmaf(w1[kk * 4 + 0], x.x, a1); a1 = fmaf(w1[kk * 4 + 1], x.y, a1);
      a1 = fmaf(w1[kk * 4 + 2], x.z, a1); a1 = fmaf(w1[kk * 4 + 3], x.w, a1);
    }
    gl[r0] = a0; gl[r1] = a1;
    __syncthreads();
    if (tid < 128) {
      float gi = gl[tid], gf = gl[128 + tid], gg = gl[256 + tid], go = gl[384 + tid];
      float c2 = sigm(gf) * creg + sigm(gi) * tanh_(gg);
      float h2 = sigm(go) * tanh_(c2);
      creg = c2;
      ohl[tid] = h2;
      oh_g[(size_t)t * 1024 + e * 128 + tid] = h2;
    }
    __syncthreads();
  }
}

// ---------------------------------------------------------------------------
// phaseD: parallel over t: softmaxes
// ---------------------------------------------------------------------------
__global__ void phaseD(const float* __restrict__ oh_g,
                       const float* __restrict__ Wtar, const float* __restrict__ btar,
                       const float* __restrict__ Wdir, const float* __restrict__ bdir,
                       float* __restrict__ outp) {
  __shared__ float ohl[1024];
  const int t = blockIdx.x, tid = threadIdx.x;  // 64 threads
  for (int idx = tid; idx < 1024; idx += 64) ohl[idx] = oh_g[(size_t)t * 1024 + idx];
  __syncthreads();
  const int f = tid;
  for (int e = 0; e < E_; ++e) {
    float acc = btar[f];
    const float* wr = Wtar + f * 128;
    #pragma unroll 4
    for (int k = 0; k < 128; ++k) acc = fmaf(wr[k], ohl[e * 128 + k], acc);
    float m = acc;
    #pragma unroll
    for (int off = 32; off; off >>= 1) m = fmaxf(m, __shfl_xor(m, off, 64));
    float ex = __expf(acc - m);
    float s = ex;
    #pragma unroll
    for (int off = 32; off; off >>= 1) s += __shfl_xor(s, off, 64);
    outp[((size_t)t * 8 + e) * 64 + f] = ex / s;
  }
  if (tid < 8) {
    int e = tid;
    float d0 = bdir[0], d1 = bdir[1], d2 = bdir[2];
    #pragma unroll 4
    for (int k = 0; k < 128; ++k) {
      float x = ohl[e * 128 + k];
      d0 = fmaf(Wdir[k], x, d0);
      d1 = fmaf(Wdir[128 + k], x, d1);
      d2 = fmaf(Wdir[256 + k], x, d2);
    }
    float m = fmaxf(d0, fmaxf(d1, d2));
    float x0 = __expf(d0 - m), x1 = __expf(d1 - m), x2 = __expf(d2 - m);
    float s = x0 + x1 + x2;
    float* dp = outp + (size_t)T_ * 8 * 64 + ((size_t)t * 8 + e) * 3;
    dp[0] = x0 / s; dp[1] = x1 / s; dp[2] = x2 / s;
  }
}

extern "C" void kernel_launch(void* const* d_in, const int* in_sizes, int n_in,
                              void* d_out, int out_size, void* d_ws, size_t ws_size,
                              hipStream_t stream) {
  (void)in_sizes; (void)n_in; (void)out_size; (void)ws_size;
  const float* feat   = (const float*)d_in[0];
  const float* pre_h0 = (const float*)d_in[1];
  const float* pre_c0 = (const float*)d_in[2];
  const float* out_h0 = (const float*)d_in[3];
  const float* out_c0 = (const float*)d_in[4];
  const float* Wih_p0 = (const float*)d_in[5];
  const float* Whh_p0 = (const float*)d_in[6];
  const float* b_p0   = (const float*)d_in[7];
  const float* Wih_p1 = (const float*)d_in[8];
  const float* Whh_p1 = (const float*)d_in[9];
  const float* b_p1   = (const float*)d_in[10];
  const float* Wfc    = (const float*)d_in[11];
  const float* bfc    = (const float*)d_in[12];
  const float* Wih_c0 = (const float*)d_in[13];
  const float* Whh_c0 = (const float*)d_in[14];
  const float* b_c0   = (const float*)d_in[15];
  const float* Wih_c1 = (const float*)d_in[16];
  const float* Whh_c1 = (const float*)d_in[17];
  const float* b_c1   = (const float*)d_in[18];
  const float* Wih_o  = (const float*)d_in[19];
  const float* Whh_o  = (const float*)d_in[20];
  const float* b_o    = (const float*)d_in[21];
  const float* Wtar   = (const float*)d_in[22];
  const float* btar   = (const float*)d_in[23];
  const float* Wdir   = (const float*)d_in[24];
  const float* bdir   = (const float*)d_in[25];
  float* outp = (float*)d_out;

  float* ws = (float*)d_ws;
  size_t off = 0;
  float* pre_outB = ws + off; off += (size_t)T_ * E_ * 128;
  float* opre1    = ws + off; off += (size_t)T_ * 512;
  float* oh_g     = ws + off; off += (size_t)T_ * E_ * 128;
  float* wt_p0    = ws + off; off += (size_t)448 * 1024;
  float* wt_p1    = ws + off; off += (size_t)512 * 1024;
  float* wt_c0    = ws + off; off += (size_t)256 * 512;
  float* wt_c1    = ws + off; off += (size_t)256 * 512;
  float* wt_o1    = ws + off; off += (size_t)256 * 512;
  float* wt_o2    = ws + off; off += (size_t)192 * 512;
  float* h0all    = ws + off; off += (size_t)T_ * 2048;
  float* h1all    = ws + off; off += (size_t)T_ * 2048;
  __hip_bfloat16* opre2 = (__hip_bfloat16*)(ws + off);
  off += (size_t)T_ * E_ * 512 / 2;
  int* bars  = (int*)(ws + off);        // 2 * T * 16 ints
  int* barsA = bars;
  int* barsB = bars + T_ * 16;

  initK<<<dim3(512), dim3(256), 0, stream>>>(
      Wih_p0, Whh_p0, Wih_p1, Whh_p1, Wih_c0, Whh_c0, Wih_c1, Whh_c1, Wih_o,
      wt_p0, wt_p1, wt_c0, wt_c1, wt_o1, wt_o2, bars);
  opre2K<<<dim3(T_), dim3(256), 0, stream>>>(feat, wt_o2, opre2);
  phaseA<<<dim3(32), dim3(256), 0, stream>>>(
      feat, pre_h0, pre_c0, wt_p0, wt_p1, b_p0, b_p1, h0all, h1all, barsA, barsB);
  fcK<<<dim3(T_), dim3(256), 0, stream>>>(h1all, Wfc, bfc, pre_outB);
  phaseB<<<dim3(T_ / 8), dim3(256), 0, stream>>>(
      pre_outB, wt_c0, wt_c1, b_c0, b_c1, wt_o1, b_o, opre1);
  phaseC<<<dim3(E_), dim3(256), 0, stream>>>(
      opre1, opre2, Whh_o, out_h0, out_c0, oh_g);
  phaseD<<<dim3(T_), dim3(64), 0, stream>>>(oh_g, Wtar, btar, Wdir, bdir, outp);
}